// Round 10
// baseline (642.543 us; speedup 1.0000x reference)
//
#include <hip/hip_runtime.h>
#include <math.h>

#define ROWS_TOTAL 8192
#define KDIM 1024
#define NPROTO 32
#define RNK 16
#define OUTD 1024
#define TIE_EPS 1.30e-4
#define CHUNK 4

// ---------------------------------------------------------------------------
// Kernel 1: routing (numerics identical to the PASSING round-7 kernel).
// ---------------------------------------------------------------------------
__global__ __launch_bounds__(256) void route_kernel(
    const float* __restrict__ x, const float* __restrict__ proto,
    const float* __restrict__ temp, float4* __restrict__ route,
    int* __restrict__ counts)
{
    __shared__ float Xs[16][68];
    __shared__ float Ps[64][33];
    __shared__ double x2s[16];
    __shared__ double p2s[32];
    __shared__ int lcnt[64];

    const int tid = threadIdx.x;
    const int rowbase = blockIdx.x * 16;
    const int frow = tid >> 4;
    const int fq   = tid & 15;
    const int c    = tid & 31;
    const int rg   = tid >> 5;

    if (tid < 64) lcnt[tid] = 0;

    double xsq = 0.0, p2a = 0.0, p2b = 0.0;
    double acc0 = 0.0, acc1 = 0.0;

    for (int kc = 0; kc < KDIM; kc += 64) {
        float4 xv = *(const float4*)(x + (rowbase + frow) * KDIM + kc + 4 * fq);
        xsq = fma((double)xv.x, (double)xv.x, xsq);
        xsq = fma((double)xv.y, (double)xv.y, xsq);
        xsq = fma((double)xv.z, (double)xv.z, xsq);
        xsq = fma((double)xv.w, (double)xv.w, xsq);
        *(float4*)(&Xs[frow][4 * fq]) = xv;
        float4 pa = *(const float4*)(proto + frow * KDIM + kc + 4 * fq);
        float4 pb = *(const float4*)(proto + (frow + 16) * KDIM + kc + 4 * fq);
        p2a = fma((double)pa.x, (double)pa.x, p2a);
        p2a = fma((double)pa.y, (double)pa.y, p2a);
        p2a = fma((double)pa.z, (double)pa.z, p2a);
        p2a = fma((double)pa.w, (double)pa.w, p2a);
        p2b = fma((double)pb.x, (double)pb.x, p2b);
        p2b = fma((double)pb.y, (double)pb.y, p2b);
        p2b = fma((double)pb.z, (double)pb.z, p2b);
        p2b = fma((double)pb.w, (double)pb.w, p2b);
        Ps[4 * fq + 0][frow] = pa.x;
        Ps[4 * fq + 1][frow] = pa.y;
        Ps[4 * fq + 2][frow] = pa.z;
        Ps[4 * fq + 3][frow] = pa.w;
        Ps[4 * fq + 0][frow + 16] = pb.x;
        Ps[4 * fq + 1][frow + 16] = pb.y;
        Ps[4 * fq + 2][frow + 16] = pb.z;
        Ps[4 * fq + 3][frow + 16] = pb.w;
        __syncthreads();
        #pragma unroll
        for (int k = 0; k < 64; k += 4) {
            float4 xa = *(const float4*)(&Xs[2 * rg][k]);
            float4 xb = *(const float4*)(&Xs[2 * rg + 1][k]);
            double q0 = (double)Ps[k][c],     q1 = (double)Ps[k + 1][c];
            double q2 = (double)Ps[k + 2][c], q3 = (double)Ps[k + 3][c];
            acc0 = fma((double)xa.x, q0, acc0);
            acc0 = fma((double)xa.y, q1, acc0);
            acc0 = fma((double)xa.z, q2, acc0);
            acc0 = fma((double)xa.w, q3, acc0);
            acc1 = fma((double)xb.x, q0, acc1);
            acc1 = fma((double)xb.y, q1, acc1);
            acc1 = fma((double)xb.z, q2, acc1);
            acc1 = fma((double)xb.w, q3, acc1);
        }
        __syncthreads();
    }

    #pragma unroll
    for (int m = 1; m < 16; m <<= 1) {
        xsq += __shfl_xor(xsq, m);
        p2a += __shfl_xor(p2a, m);
        p2b += __shfl_xor(p2b, m);
    }
    if (fq == 0) { x2s[frow] = xsq; p2s[frow] = p2a; p2s[frow + 16] = p2b; }
    __syncthreads();

    const double tmp = (double)fmaxf(fabsf(temp[0]), 0.1f);
    const double myp2 = p2s[c];

    #pragma unroll
    for (int which = 0; which < 2; ++which) {
        double key = myp2 - 2.0 * (which ? acc1 : acc0);
        double k1 = key, k2 = 1.0e300, k3 = 1.1e300;
        int    i1 = c,   i2 = 64,      i3 = 65;
        #pragma unroll
        for (int m = 1; m < 32; m <<= 1) {
            double b1 = __shfl_xor(k1, m), b2 = __shfl_xor(k2, m), b3 = __shfl_xor(k3, m);
            int    j1 = __shfl_xor(i1, m), j2 = __shfl_xor(i2, m), j3 = __shfl_xor(i3, m);
            bool c1 = k1 <= b1;
            double m1 = c1 ? k1 : b1, M1 = c1 ? b1 : k1;
            int   mi1 = c1 ? i1 : j1, Mi1 = c1 ? j1 : i1;
            bool c2 = k2 <= b2;
            double m2 = c2 ? k2 : b2;
            int   mi2 = c2 ? i2 : j2;
            bool c3 = k3 <= b3;
            double m3 = c3 ? k3 : b3;
            int   mi3 = c3 ? i3 : j3;
            bool c4 = M1 <= m2;
            double t2 = c4 ? M1 : m2,  T2 = c4 ? m2 : M1;
            int   ti2 = c4 ? Mi1 : mi2, Ti2 = c4 ? mi2 : Mi1;
            bool c5 = T2 <= m3;
            k1 = m1; i1 = mi1;
            k2 = t2; i2 = ti2;
            k3 = c5 ? T2 : m3; i3 = c5 ? Ti2 : mi3;
        }
        if (c == 0) {
            const int row = rowbase + 2 * rg + which;
            bool tie = (k3 - k2) < TIE_EPS;
            bool take3 = tie && (i3 < i2);
            double ksel = take3 ? k3 : k2;
            int    isel = take3 ? i3 : i2;
            double x2 = x2s[2 * rg + which];
            double d0 = sqrt(fmax(x2 + k1, 0.0));
            double d1 = sqrt(fmax(x2 + ksel, 0.0));
            float e  = expf((float)((d0 - d1) / tmp));
            float w0 = 1.f / (1.f + e);
            route[row] = make_float4(__int_as_float(i1), __int_as_float(isel),
                                     w0, e * w0);
            atomicAdd(&lcnt[i1], 1);
            atomicAdd(&lcnt[32 + isel], 1);
        }
    }
    __syncthreads();
    if (tid < 64) atomicAdd(&counts[tid], lcnt[tid]);
}

// counts[64] -> per-32-segment exclusive prefix (scatter cursors) + segs.
__global__ __launch_bounds__(64) void scan_kernel(int* __restrict__ counts,
                                                  int2* __restrict__ segs)
{
    const int tid = threadIdx.x;
    int v = counts[tid];
    int sum = v;
    #pragma unroll
    for (int off = 1; off < 32; off <<= 1) {
        int u = __shfl_up(sum, off, 32);
        if ((tid & 31) >= off) sum += u;
    }
    int excl = sum - v;
    counts[tid] = excl;
    segs[tid] = make_int2(excl, excl + v);
}

__global__ __launch_bounds__(256) void scatter_kernel(
    const float4* __restrict__ route, int* __restrict__ counts,
    int* __restrict__ rowlist0, int* __restrict__ rowlist1)
{
    __shared__ int lcnt[64];
    __shared__ int gbase[64];
    const int tid = threadIdx.x;
    const int i = blockIdx.x * 256 + tid;
    if (tid < 64) lcnt[tid] = 0;
    __syncthreads();
    float4 rt = route[i];
    int p0 = __float_as_int(rt.x);
    int p1 = __float_as_int(rt.y);
    int lp0 = atomicAdd(&lcnt[p0], 1);
    int lp1 = atomicAdd(&lcnt[32 + p1], 1);
    __syncthreads();
    if (tid < 64) gbase[tid] = atomicAdd(&counts[tid], lcnt[tid]);
    __syncthreads();
    rowlist0[gbase[p0] + lp0] = i;
    rowlist1[gbase[32 + p1] + lp1] = i;
}

// ---------------------------------------------------------------------------
// Apply v4: block = (proto=blockIdx.y, chunk-slot=blockIdx.x), grid-stride
// over 4-row chunks of the proto's sorted segment. All A/B reads COALESCED:
//  h: rank-sequential, lanes read consecutive B float4s (same stream on all
//     4 waves -> L1 broadcast), dot vs LDS x, 6-shfl reduce.
//  y: stream A[p] flat (lane l reads float4 k*64+l), dot with h-quarter
//     (l&3), xor-shfl(1,2) reduce, bounce via LDS (x buffer reused), then
//     coalesced float4 epilogue stores. slot1 accumulates (stream-ordered).
// LDS ~16.5KB -> 8 blocks/CU.
// ---------------------------------------------------------------------------
__global__ __launch_bounds__(256) void apply4_kernel(
    const float* __restrict__ x, const float* __restrict__ A,
    const float* __restrict__ B, const float* __restrict__ bias,
    const float4* __restrict__ route, const int* __restrict__ rowlist,
    const int2* __restrict__ segs, float* __restrict__ out, int slot)
{
    __shared__ __align__(16) float buf[CHUNK * KDIM];   // x, then ys (16 KB)
    __shared__ __align__(16) float hs[CHUNK][16];
    __shared__ int rows[CHUNK];
    __shared__ float wrow[CHUNK];

    const int tid = threadIdx.x;
    const int l   = tid & 63;
    const int wv  = tid >> 6;        // wave id == row slot in chunk
    const int p   = blockIdx.y;
    const int2 seg = segs[slot * 32 + p];

    const float4* Bp = (const float4*)(B + (size_t)p * RNK * KDIM);
    const float4* Ap = (const float4*)(A + (size_t)p * OUTD * RNK);
    const float4* bp = (const float4*)(bias + (size_t)p * OUTD);

    for (int c = blockIdx.x; ; c += 64) {
        const int base = seg.x + c * CHUNK;
        if (base >= seg.y) break;
        const int m = min(CHUNK, seg.y - base);

        if (tid < CHUNK) {
            int rr = rowlist[base + min(tid, m - 1)];
            rows[tid] = rr;
            float4 rt = route[rr];
            wrow[tid] = slot ? rt.w : rt.z;
        }
        __syncthreads();

        // stage x rows (coalesced; duplicates for tail slots are harmless)
        #pragma unroll
        for (int i = 0; i < CHUNK; ++i) {
            float4 v = *(const float4*)(x + (size_t)rows[i] * KDIM + tid * 4);
            *(float4*)(&buf[i * KDIM + tid * 4]) = v;
        }
        __syncthreads();

        // ---- h phase: wave wv -> row wv; rank-sequential coalesced B ----
        {
            const float4* Xw = (const float4*)(&buf[wv * KDIM]);
            float4 x0 = Xw[0 * 64 + l];
            float4 x1 = Xw[1 * 64 + l];
            float4 x2 = Xw[2 * 64 + l];
            float4 x3 = Xw[3 * 64 + l];
            #pragma unroll
            for (int r = 0; r < RNK; ++r) {
                float4 b0 = Bp[r * 256 + 0 * 64 + l];
                float4 b1 = Bp[r * 256 + 1 * 64 + l];
                float4 b2 = Bp[r * 256 + 2 * 64 + l];
                float4 b3 = Bp[r * 256 + 3 * 64 + l];
                float a0 = fmaf(x0.x, b0.x, fmaf(x0.y, b0.y, fmaf(x0.z, b0.z, x0.w * b0.w)));
                float a1 = fmaf(x1.x, b1.x, fmaf(x1.y, b1.y, fmaf(x1.z, b1.z, x1.w * b1.w)));
                float a2 = fmaf(x2.x, b2.x, fmaf(x2.y, b2.y, fmaf(x2.z, b2.z, x2.w * b2.w)));
                float a3 = fmaf(x3.x, b3.x, fmaf(x3.y, b3.y, fmaf(x3.z, b3.z, x3.w * b3.w)));
                float t = (a0 + a1) + (a2 + a3);
                t += __shfl_xor(t, 1);
                t += __shfl_xor(t, 2);
                t += __shfl_xor(t, 4);
                t += __shfl_xor(t, 8);
                t += __shfl_xor(t, 16);
                t += __shfl_xor(t, 32);
                if (l == 0) hs[wv][r] = t;
            }
        }
        __syncthreads();   // hs ready; x buffer now dead

        // ---- y phase: stream A[p] coalesced; ys into reused buffer ----
        {
            float4 hq = *(const float4*)(&hs[wv][4 * (l & 3)]);
            float* ys = &buf[wv * KDIM];
            #pragma unroll 8
            for (int k = 0; k < 64; ++k) {
                float4 a4 = Ap[k * 64 + l];
                float v = fmaf(a4.x, hq.x, fmaf(a4.y, hq.y, fmaf(a4.z, hq.z, a4.w * hq.w)));
                v += __shfl_xor(v, 1);
                v += __shfl_xor(v, 2);
                if ((l & 3) == 0) ys[16 * k + (l >> 2)] = v;
            }
        }
        __syncthreads();

        // ---- epilogue: coalesced float4 stores ----
        if (wv < m) {
            const float wgt = wrow[wv];
            const float4* ys4 = (const float4*)(&buf[wv * KDIM]);
            float* orow = out + (size_t)rows[wv] * OUTD;
            #pragma unroll
            for (int j = 0; j < 4; ++j) {
                const int f4 = j * 64 + l;
                float4 yv = ys4[f4];
                float4 bb = bp[f4];
                float4 v = make_float4(wgt * (yv.x + bb.x), wgt * (yv.y + bb.y),
                                       wgt * (yv.z + bb.z), wgt * (yv.w + bb.w));
                float4* dst = (float4*)(orow + f4 * 4);
                if (slot) {
                    float4 old = *dst;
                    v.x += old.x; v.y += old.y; v.z += old.z; v.w += old.w;
                }
                *dst = v;
            }
        }
        __syncthreads();   // before buf reuse in next chunk
    }
}

extern "C" void kernel_launch(void* const* d_in, const int* in_sizes, int n_in,
                              void* d_out, int out_size, void* d_ws, size_t ws_size,
                              hipStream_t stream) {
    const float* x     = (const float*)d_in[0];
    const float* proto = (const float*)d_in[1];
    const float* B     = (const float*)d_in[2];
    const float* A     = (const float*)d_in[3];
    const float* bias  = (const float*)d_in[4];
    const float* temp  = (const float*)d_in[5];
    float* out = (float*)d_out;

    float4* route   = (float4*)d_ws;                        // 128 KB
    int* rowlist0   = (int*)((char*)d_ws + 131072);         // 32 KB
    int* rowlist1   = rowlist0 + ROWS_TOTAL;                // 32 KB
    int* counts     = rowlist1 + ROWS_TOTAL;                // 256 B
    int2* segs      = (int2*)(counts + 64);                 // 512 B

    hipMemsetAsync(counts, 0, 64 * sizeof(int), stream);
    route_kernel<<<ROWS_TOTAL / 16, 256, 0, stream>>>(x, proto, temp, route, counts);
    scan_kernel<<<1, 64, 0, stream>>>(counts, segs);
    scatter_kernel<<<ROWS_TOTAL / 256, 256, 0, stream>>>(route, counts, rowlist0, rowlist1);
    dim3 agrid(64, NPROTO);
    apply4_kernel<<<agrid, 256, 0, stream>>>(x, A, B, bias, route, rowlist0, segs, out, 0);
    apply4_kernel<<<agrid, 256, 0, stream>>>(x, A, B, bias, route, rowlist1, segs, out, 1);
}

// Round 11
// 341.408 us; speedup vs baseline: 1.8820x; 1.8820x over previous
//
#include <hip/hip_runtime.h>
#include <math.h>

#define ROWS_TOTAL 8192
#define KDIM 1024
#define NPROTO 32
#define RNK 16
#define OUTD 1024
#define TIE_EPS 1.30e-4
#define CROWS 16

// ---------------------------------------------------------------------------
// Kernel 1: routing (numerics identical to the PASSING round-7 kernel).
// ---------------------------------------------------------------------------
__global__ __launch_bounds__(256) void route_kernel(
    const float* __restrict__ x, const float* __restrict__ proto,
    const float* __restrict__ temp, float4* __restrict__ route,
    int* __restrict__ counts)
{
    __shared__ float Xs[16][68];
    __shared__ float Ps[64][33];
    __shared__ double x2s[16];
    __shared__ double p2s[32];
    __shared__ int lcnt[64];

    const int tid = threadIdx.x;
    const int rowbase = blockIdx.x * 16;
    const int frow = tid >> 4;
    const int fq   = tid & 15;
    const int c    = tid & 31;
    const int rg   = tid >> 5;

    if (tid < 64) lcnt[tid] = 0;

    double xsq = 0.0, p2a = 0.0, p2b = 0.0;
    double acc0 = 0.0, acc1 = 0.0;

    for (int kc = 0; kc < KDIM; kc += 64) {
        float4 xv = *(const float4*)(x + (rowbase + frow) * KDIM + kc + 4 * fq);
        xsq = fma((double)xv.x, (double)xv.x, xsq);
        xsq = fma((double)xv.y, (double)xv.y, xsq);
        xsq = fma((double)xv.z, (double)xv.z, xsq);
        xsq = fma((double)xv.w, (double)xv.w, xsq);
        *(float4*)(&Xs[frow][4 * fq]) = xv;
        float4 pa = *(const float4*)(proto + frow * KDIM + kc + 4 * fq);
        float4 pb = *(const float4*)(proto + (frow + 16) * KDIM + kc + 4 * fq);
        p2a = fma((double)pa.x, (double)pa.x, p2a);
        p2a = fma((double)pa.y, (double)pa.y, p2a);
        p2a = fma((double)pa.z, (double)pa.z, p2a);
        p2a = fma((double)pa.w, (double)pa.w, p2a);
        p2b = fma((double)pb.x, (double)pb.x, p2b);
        p2b = fma((double)pb.y, (double)pb.y, p2b);
        p2b = fma((double)pb.z, (double)pb.z, p2b);
        p2b = fma((double)pb.w, (double)pb.w, p2b);
        Ps[4 * fq + 0][frow] = pa.x;
        Ps[4 * fq + 1][frow] = pa.y;
        Ps[4 * fq + 2][frow] = pa.z;
        Ps[4 * fq + 3][frow] = pa.w;
        Ps[4 * fq + 0][frow + 16] = pb.x;
        Ps[4 * fq + 1][frow + 16] = pb.y;
        Ps[4 * fq + 2][frow + 16] = pb.z;
        Ps[4 * fq + 3][frow + 16] = pb.w;
        __syncthreads();
        #pragma unroll
        for (int k = 0; k < 64; k += 4) {
            float4 xa = *(const float4*)(&Xs[2 * rg][k]);
            float4 xb = *(const float4*)(&Xs[2 * rg + 1][k]);
            double q0 = (double)Ps[k][c],     q1 = (double)Ps[k + 1][c];
            double q2 = (double)Ps[k + 2][c], q3 = (double)Ps[k + 3][c];
            acc0 = fma((double)xa.x, q0, acc0);
            acc0 = fma((double)xa.y, q1, acc0);
            acc0 = fma((double)xa.z, q2, acc0);
            acc0 = fma((double)xa.w, q3, acc0);
            acc1 = fma((double)xb.x, q0, acc1);
            acc1 = fma((double)xb.y, q1, acc1);
            acc1 = fma((double)xb.z, q2, acc1);
            acc1 = fma((double)xb.w, q3, acc1);
        }
        __syncthreads();
    }

    #pragma unroll
    for (int m = 1; m < 16; m <<= 1) {
        xsq += __shfl_xor(xsq, m);
        p2a += __shfl_xor(p2a, m);
        p2b += __shfl_xor(p2b, m);
    }
    if (fq == 0) { x2s[frow] = xsq; p2s[frow] = p2a; p2s[frow + 16] = p2b; }
    __syncthreads();

    const double tmp = (double)fmaxf(fabsf(temp[0]), 0.1f);
    const double myp2 = p2s[c];

    #pragma unroll
    for (int which = 0; which < 2; ++which) {
        double key = myp2 - 2.0 * (which ? acc1 : acc0);
        double k1 = key, k2 = 1.0e300, k3 = 1.1e300;
        int    i1 = c,   i2 = 64,      i3 = 65;
        #pragma unroll
        for (int m = 1; m < 32; m <<= 1) {
            double b1 = __shfl_xor(k1, m), b2 = __shfl_xor(k2, m), b3 = __shfl_xor(k3, m);
            int    j1 = __shfl_xor(i1, m), j2 = __shfl_xor(i2, m), j3 = __shfl_xor(i3, m);
            bool c1 = k1 <= b1;
            double m1 = c1 ? k1 : b1, M1 = c1 ? b1 : k1;
            int   mi1 = c1 ? i1 : j1, Mi1 = c1 ? j1 : i1;
            bool c2 = k2 <= b2;
            double m2 = c2 ? k2 : b2;
            int   mi2 = c2 ? i2 : j2;
            bool c3 = k3 <= b3;
            double m3 = c3 ? k3 : b3;
            int   mi3 = c3 ? i3 : j3;
            bool c4 = M1 <= m2;
            double t2 = c4 ? M1 : m2,  T2 = c4 ? m2 : M1;
            int   ti2 = c4 ? Mi1 : mi2, Ti2 = c4 ? mi2 : Mi1;
            bool c5 = T2 <= m3;
            k1 = m1; i1 = mi1;
            k2 = t2; i2 = ti2;
            k3 = c5 ? T2 : m3; i3 = c5 ? Ti2 : mi3;
        }
        if (c == 0) {
            const int row = rowbase + 2 * rg + which;
            bool tie = (k3 - k2) < TIE_EPS;
            bool take3 = tie && (i3 < i2);
            double ksel = take3 ? k3 : k2;
            int    isel = take3 ? i3 : i2;
            double x2 = x2s[2 * rg + which];
            double d0 = sqrt(fmax(x2 + k1, 0.0));
            double d1 = sqrt(fmax(x2 + ksel, 0.0));
            float e  = expf((float)((d0 - d1) / tmp));
            float w0 = 1.f / (1.f + e);
            route[row] = make_float4(__int_as_float(i1), __int_as_float(isel),
                                     w0, e * w0);
            atomicAdd(&lcnt[i1], 1);
            atomicAdd(&lcnt[32 + isel], 1);
        }
    }
    __syncthreads();
    if (tid < 64) atomicAdd(&counts[tid], lcnt[tid]);
}

__global__ __launch_bounds__(64) void scan_kernel(int* __restrict__ counts,
                                                  int2* __restrict__ segs)
{
    const int tid = threadIdx.x;
    int v = counts[tid];
    int sum = v;
    #pragma unroll
    for (int off = 1; off < 32; off <<= 1) {
        int u = __shfl_up(sum, off, 32);
        if ((tid & 31) >= off) sum += u;
    }
    int excl = sum - v;
    counts[tid] = excl;
    segs[tid] = make_int2(excl, excl + v);
}

__global__ __launch_bounds__(256) void scatter_kernel(
    const float4* __restrict__ route, int* __restrict__ counts,
    int* __restrict__ rowlist0, int* __restrict__ rowlist1)
{
    __shared__ int lcnt[64];
    __shared__ int gbase[64];
    const int tid = threadIdx.x;
    const int i = blockIdx.x * 256 + tid;
    if (tid < 64) lcnt[tid] = 0;
    __syncthreads();
    float4 rt = route[i];
    int p0 = __float_as_int(rt.x);
    int p1 = __float_as_int(rt.y);
    int lp0 = atomicAdd(&lcnt[p0], 1);
    int lp1 = atomicAdd(&lcnt[32 + p1], 1);
    __syncthreads();
    if (tid < 64) gbase[tid] = atomicAdd(&counts[tid], lcnt[tid]);
    __syncthreads();
    rowlist0[gbase[p0] + lp0] = i;
    rowlist1[gbase[32 + p1] + lp1] = i;
}

// ---------------------------------------------------------------------------
// Transpose kernel: Bt[p][k][r] = B[p][r][k], At[p][r][o] = A[p][o][r].
// One block per proto; LDS tile transposes; all global accesses coalesced.
// ---------------------------------------------------------------------------
__global__ __launch_bounds__(256) void transpose_kernel(
    const float* __restrict__ A, const float* __restrict__ B,
    float* __restrict__ At, float* __restrict__ Bt)
{
    __shared__ float T[16 * 68];   // B chunk [16 r][64 k] padded
    __shared__ float U[64 * 20];   // A chunk [64 o][16 r] padded
    const int tid = threadIdx.x;
    const int p = blockIdx.x;
    const float4* B4 = (const float4*)(B + (size_t)p * RNK * KDIM);
    const float4* A4 = (const float4*)(A + (size_t)p * OUTD * RNK);
    float4* Bt4 = (float4*)(Bt + (size_t)p * KDIM * RNK);
    float4* At4 = (float4*)(At + (size_t)p * RNK * OUTD);

    for (int c = 0; c < 16; ++c) {
        {   // load B [16 r][64 k]
            int r = tid >> 4, kk = tid & 15;
            float4 v = B4[r * 256 + c * 16 + kk];
            *(float4*)&T[r * 68 + kk * 4] = v;
        }
        {   // load A [64 o][16 r]
            int o = tid >> 2, rq = tid & 3;
            float4 v = A4[(c * 64 + o) * 4 + rq];
            *(float4*)&U[o * 20 + rq * 4] = v;
        }
        __syncthreads();
        {   // store Bt [64 k][16 r]
            int k = tid >> 2, rq = tid & 3;
            float4 g = make_float4(T[(rq * 4 + 0) * 68 + k], T[(rq * 4 + 1) * 68 + k],
                                   T[(rq * 4 + 2) * 68 + k], T[(rq * 4 + 3) * 68 + k]);
            Bt4[(c * 64 + k) * 4 + rq] = g;
        }
        {   // store At [16 r][64 o]
            int r = tid >> 4, ow = tid & 15;
            float4 g = make_float4(U[(ow * 4 + 0) * 20 + r], U[(ow * 4 + 1) * 20 + r],
                                   U[(ow * 4 + 2) * 20 + r], U[(ow * 4 + 3) * 20 + r]);
            At4[r * 256 + c * 16 + ow] = g;
        }
        __syncthreads();
    }
}

// ---------------------------------------------------------------------------
// Apply v5: block = (chunk-slot, proto); 16 rows per chunk from the sorted
// rowlist. All global reads coalesced via Bt/At:
//  h: thread (rw, kseg), k = 16i+kseg interleaved; x scalar coalesced, Bt row
//     64B coalesced; 16 independent rank-accumulators; LDS partial reduce.
//  y: thread (rw, o); At rows coalesced float4; 16 output float4s per thread.
// slot0 stores w*y+wb, slot1 accumulates (stream-ordered, race-free).
// ---------------------------------------------------------------------------
__global__ __launch_bounds__(256) void apply5_kernel(
    const float* __restrict__ x, const float* __restrict__ At,
    const float* __restrict__ Bt, const float* __restrict__ bias,
    const float4* __restrict__ route, const int* __restrict__ rowlist,
    const int2* __restrict__ segs, float* __restrict__ out, int slot)
{
    __shared__ float part[CROWS][16][17];   // [row][kseg][rank]
    __shared__ float hs[CROWS][16];
    __shared__ int rows[CROWS];
    __shared__ float wrow[CROWS];

    const int tid = threadIdx.x;
    const int p = blockIdx.y;
    const int2 seg = segs[slot * 32 + p];
    const float4* Btp = (const float4*)(Bt + (size_t)p * KDIM * RNK);
    const float4* Atp = (const float4*)(At + (size_t)p * RNK * OUTD);
    const float4* bp  = (const float4*)(bias + (size_t)p * OUTD);

    for (int c = blockIdx.x; ; c += gridDim.x) {
        const int base = seg.x + c * CROWS;
        if (base >= seg.y) break;
        const int m = min(CROWS, seg.y - base);

        if (tid < CROWS) {
            int rr = rowlist[base + min(tid, m - 1)];
            rows[tid] = rr;
            float4 rt = route[rr];
            wrow[tid] = slot ? rt.w : rt.z;
        }
        __syncthreads();

        // ---- h phase ----
        {
            const int rw = tid >> 4, kseg = tid & 15;
            const float* xr = x + (size_t)rows[rw] * KDIM;
            float4 a0 = {0,0,0,0}, a1 = {0,0,0,0}, a2 = {0,0,0,0}, a3 = {0,0,0,0};
            #pragma unroll 8
            for (int i = 0; i < 64; ++i) {
                const int k = i * 16 + kseg;
                float xv = xr[k];
                float4 b0 = Btp[k * 4 + 0];
                float4 b1 = Btp[k * 4 + 1];
                float4 b2 = Btp[k * 4 + 2];
                float4 b3 = Btp[k * 4 + 3];
                a0.x = fmaf(xv, b0.x, a0.x); a0.y = fmaf(xv, b0.y, a0.y);
                a0.z = fmaf(xv, b0.z, a0.z); a0.w = fmaf(xv, b0.w, a0.w);
                a1.x = fmaf(xv, b1.x, a1.x); a1.y = fmaf(xv, b1.y, a1.y);
                a1.z = fmaf(xv, b1.z, a1.z); a1.w = fmaf(xv, b1.w, a1.w);
                a2.x = fmaf(xv, b2.x, a2.x); a2.y = fmaf(xv, b2.y, a2.y);
                a2.z = fmaf(xv, b2.z, a2.z); a2.w = fmaf(xv, b2.w, a2.w);
                a3.x = fmaf(xv, b3.x, a3.x); a3.y = fmaf(xv, b3.y, a3.y);
                a3.z = fmaf(xv, b3.z, a3.z); a3.w = fmaf(xv, b3.w, a3.w);
            }
            float* pr = &part[rw][kseg][0];
            pr[0]  = a0.x; pr[1]  = a0.y; pr[2]  = a0.z; pr[3]  = a0.w;
            pr[4]  = a1.x; pr[5]  = a1.y; pr[6]  = a1.z; pr[7]  = a1.w;
            pr[8]  = a2.x; pr[9]  = a2.y; pr[10] = a2.z; pr[11] = a2.w;
            pr[12] = a3.x; pr[13] = a3.y; pr[14] = a3.z; pr[15] = a3.w;
        }
        __syncthreads();

        // ---- reduce over ksegs ----
        {
            const int rw = tid >> 4, r = tid & 15;
            float s = 0.f;
            #pragma unroll
            for (int ks = 0; ks < 16; ++ks) s += part[rw][ks][r];
            hs[rw][r] = s;
        }
        __syncthreads();

        // ---- y phase ----
        {
            const int rw = tid >> 4, o = tid & 15;
            if (rw < m) {
                float h[16];
                #pragma unroll
                for (int r = 0; r < 16; ++r) h[r] = hs[rw][r];
                const float wgt = wrow[rw];
                float* orow = out + (size_t)rows[rw] * OUTD;
                #pragma unroll 4
                for (int j = 0; j < 16; ++j) {
                    const int f4 = j * 16 + o;
                    float4 acc = bp[f4];
                    #pragma unroll
                    for (int r = 0; r < 16; ++r) {
                        float4 a = Atp[r * 256 + f4];
                        acc.x = fmaf(h[r], a.x, acc.x);
                        acc.y = fmaf(h[r], a.y, acc.y);
                        acc.z = fmaf(h[r], a.z, acc.z);
                        acc.w = fmaf(h[r], a.w, acc.w);
                    }
                    float4 v = make_float4(wgt * acc.x, wgt * acc.y,
                                           wgt * acc.z, wgt * acc.w);
                    float4* dst = (float4*)(orow + f4 * 4);
                    if (slot) {
                        float4 old = *dst;
                        v.x += old.x; v.y += old.y; v.z += old.z; v.w += old.w;
                    }
                    *dst = v;
                }
            }
        }
        __syncthreads();
    }
}

extern "C" void kernel_launch(void* const* d_in, const int* in_sizes, int n_in,
                              void* d_out, int out_size, void* d_ws, size_t ws_size,
                              hipStream_t stream) {
    const float* x     = (const float*)d_in[0];
    const float* proto = (const float*)d_in[1];
    const float* B     = (const float*)d_in[2];
    const float* A     = (const float*)d_in[3];
    const float* bias  = (const float*)d_in[4];
    const float* temp  = (const float*)d_in[5];
    float* out = (float*)d_out;

    char* wsb = (char*)d_ws;
    float4* route = (float4*)wsb;                      // 128 KB
    int* rowlist0 = (int*)(wsb + 131072);              // 32 KB
    int* rowlist1 = rowlist0 + ROWS_TOTAL;             // 32 KB
    int* counts   = rowlist1 + ROWS_TOTAL;             // 256 B
    int2* segs    = (int2*)(counts + 64);              // 512 B
    float* Bt     = (float*)(wsb + 262144);            // 2 MB
    float* At     = (float*)(wsb + 262144 + 2097152);  // 2 MB

    hipMemsetAsync(counts, 0, 64 * sizeof(int), stream);
    transpose_kernel<<<NPROTO, 256, 0, stream>>>(A, B, At, Bt);
    route_kernel<<<ROWS_TOTAL / 16, 256, 0, stream>>>(x, proto, temp, route, counts);
    scan_kernel<<<1, 64, 0, stream>>>(counts, segs);
    scatter_kernel<<<ROWS_TOTAL / 256, 256, 0, stream>>>(route, counts, rowlist0, rowlist1);
    dim3 agrid(16, NPROTO);
    apply5_kernel<<<agrid, 256, 0, stream>>>(x, At, Bt, bias, route, rowlist0, segs, out, 0);
    apply5_kernel<<<agrid, 256, 0, stream>>>(x, At, Bt, bias, route, rowlist1, segs, out, 1);
}

// Round 12
// 255.197 us; speedup vs baseline: 2.5178x; 1.3378x over previous
//
#include <hip/hip_runtime.h>
#include <math.h>

#define ROWS_TOTAL 8192
#define KDIM 1024
#define NPROTO 32
#define RNK 16
#define OUTD 1024
#define TIE_EPS 1.30e-4
#define CROWS 4

// ---------------------------------------------------------------------------
// Kernel 1: routing (numerics identical to the PASSING round-7 kernel).
// ---------------------------------------------------------------------------
__global__ __launch_bounds__(256) void route_kernel(
    const float* __restrict__ x, const float* __restrict__ proto,
    const float* __restrict__ temp, float4* __restrict__ route,
    int* __restrict__ counts)
{
    __shared__ float Xs[16][68];
    __shared__ float Ps[64][33];
    __shared__ double x2s[16];
    __shared__ double p2s[32];
    __shared__ int lcnt[64];

    const int tid = threadIdx.x;
    const int rowbase = blockIdx.x * 16;
    const int frow = tid >> 4;
    const int fq   = tid & 15;
    const int c    = tid & 31;
    const int rg   = tid >> 5;

    if (tid < 64) lcnt[tid] = 0;

    double xsq = 0.0, p2a = 0.0, p2b = 0.0;
    double acc0 = 0.0, acc1 = 0.0;

    for (int kc = 0; kc < KDIM; kc += 64) {
        float4 xv = *(const float4*)(x + (rowbase + frow) * KDIM + kc + 4 * fq);
        xsq = fma((double)xv.x, (double)xv.x, xsq);
        xsq = fma((double)xv.y, (double)xv.y, xsq);
        xsq = fma((double)xv.z, (double)xv.z, xsq);
        xsq = fma((double)xv.w, (double)xv.w, xsq);
        *(float4*)(&Xs[frow][4 * fq]) = xv;
        float4 pa = *(const float4*)(proto + frow * KDIM + kc + 4 * fq);
        float4 pb = *(const float4*)(proto + (frow + 16) * KDIM + kc + 4 * fq);
        p2a = fma((double)pa.x, (double)pa.x, p2a);
        p2a = fma((double)pa.y, (double)pa.y, p2a);
        p2a = fma((double)pa.z, (double)pa.z, p2a);
        p2a = fma((double)pa.w, (double)pa.w, p2a);
        p2b = fma((double)pb.x, (double)pb.x, p2b);
        p2b = fma((double)pb.y, (double)pb.y, p2b);
        p2b = fma((double)pb.z, (double)pb.z, p2b);
        p2b = fma((double)pb.w, (double)pb.w, p2b);
        Ps[4 * fq + 0][frow] = pa.x;
        Ps[4 * fq + 1][frow] = pa.y;
        Ps[4 * fq + 2][frow] = pa.z;
        Ps[4 * fq + 3][frow] = pa.w;
        Ps[4 * fq + 0][frow + 16] = pb.x;
        Ps[4 * fq + 1][frow + 16] = pb.y;
        Ps[4 * fq + 2][frow + 16] = pb.z;
        Ps[4 * fq + 3][frow + 16] = pb.w;
        __syncthreads();
        #pragma unroll
        for (int k = 0; k < 64; k += 4) {
            float4 xa = *(const float4*)(&Xs[2 * rg][k]);
            float4 xb = *(const float4*)(&Xs[2 * rg + 1][k]);
            double q0 = (double)Ps[k][c],     q1 = (double)Ps[k + 1][c];
            double q2 = (double)Ps[k + 2][c], q3 = (double)Ps[k + 3][c];
            acc0 = fma((double)xa.x, q0, acc0);
            acc0 = fma((double)xa.y, q1, acc0);
            acc0 = fma((double)xa.z, q2, acc0);
            acc0 = fma((double)xa.w, q3, acc0);
            acc1 = fma((double)xb.x, q0, acc1);
            acc1 = fma((double)xb.y, q1, acc1);
            acc1 = fma((double)xb.z, q2, acc1);
            acc1 = fma((double)xb.w, q3, acc1);
        }
        __syncthreads();
    }

    #pragma unroll
    for (int m = 1; m < 16; m <<= 1) {
        xsq += __shfl_xor(xsq, m);
        p2a += __shfl_xor(p2a, m);
        p2b += __shfl_xor(p2b, m);
    }
    if (fq == 0) { x2s[frow] = xsq; p2s[frow] = p2a; p2s[frow + 16] = p2b; }
    __syncthreads();

    const double tmp = (double)fmaxf(fabsf(temp[0]), 0.1f);
    const double myp2 = p2s[c];

    #pragma unroll
    for (int which = 0; which < 2; ++which) {
        double key = myp2 - 2.0 * (which ? acc1 : acc0);
        double k1 = key, k2 = 1.0e300, k3 = 1.1e300;
        int    i1 = c,   i2 = 64,      i3 = 65;
        #pragma unroll
        for (int m = 1; m < 32; m <<= 1) {
            double b1 = __shfl_xor(k1, m), b2 = __shfl_xor(k2, m), b3 = __shfl_xor(k3, m);
            int    j1 = __shfl_xor(i1, m), j2 = __shfl_xor(i2, m), j3 = __shfl_xor(i3, m);
            bool c1 = k1 <= b1;
            double m1 = c1 ? k1 : b1, M1 = c1 ? b1 : k1;
            int   mi1 = c1 ? i1 : j1, Mi1 = c1 ? j1 : i1;
            bool c2 = k2 <= b2;
            double m2 = c2 ? k2 : b2;
            int   mi2 = c2 ? i2 : j2;
            bool c3 = k3 <= b3;
            double m3 = c3 ? k3 : b3;
            int   mi3 = c3 ? i3 : j3;
            bool c4 = M1 <= m2;
            double t2 = c4 ? M1 : m2,  T2 = c4 ? m2 : M1;
            int   ti2 = c4 ? Mi1 : mi2, Ti2 = c4 ? mi2 : Mi1;
            bool c5 = T2 <= m3;
            k1 = m1; i1 = mi1;
            k2 = t2; i2 = ti2;
            k3 = c5 ? T2 : m3; i3 = c5 ? Ti2 : mi3;
        }
        if (c == 0) {
            const int row = rowbase + 2 * rg + which;
            bool tie = (k3 - k2) < TIE_EPS;
            bool take3 = tie && (i3 < i2);
            double ksel = take3 ? k3 : k2;
            int    isel = take3 ? i3 : i2;
            double x2 = x2s[2 * rg + which];
            double d0 = sqrt(fmax(x2 + k1, 0.0));
            double d1 = sqrt(fmax(x2 + ksel, 0.0));
            float e  = expf((float)((d0 - d1) / tmp));
            float w0 = 1.f / (1.f + e);
            route[row] = make_float4(__int_as_float(i1), __int_as_float(isel),
                                     w0, e * w0);
            atomicAdd(&lcnt[i1], 1);
            atomicAdd(&lcnt[32 + isel], 1);
        }
    }
    __syncthreads();
    if (tid < 64) atomicAdd(&counts[tid], lcnt[tid]);
}

__global__ __launch_bounds__(64) void scan_kernel(int* __restrict__ counts,
                                                  int2* __restrict__ segs)
{
    const int tid = threadIdx.x;
    int v = counts[tid];
    int sum = v;
    #pragma unroll
    for (int off = 1; off < 32; off <<= 1) {
        int u = __shfl_up(sum, off, 32);
        if ((tid & 31) >= off) sum += u;
    }
    int excl = sum - v;
    counts[tid] = excl;
    segs[tid] = make_int2(excl, excl + v);
}

__global__ __launch_bounds__(256) void scatter_kernel(
    const float4* __restrict__ route, int* __restrict__ counts,
    int* __restrict__ rowlist0, int* __restrict__ rowlist1)
{
    __shared__ int lcnt[64];
    __shared__ int gbase[64];
    const int tid = threadIdx.x;
    const int i = blockIdx.x * 256 + tid;
    if (tid < 64) lcnt[tid] = 0;
    __syncthreads();
    float4 rt = route[i];
    int p0 = __float_as_int(rt.x);
    int p1 = __float_as_int(rt.y);
    int lp0 = atomicAdd(&lcnt[p0], 1);
    int lp1 = atomicAdd(&lcnt[32 + p1], 1);
    __syncthreads();
    if (tid < 64) gbase[tid] = atomicAdd(&counts[tid], lcnt[tid]);
    __syncthreads();
    rowlist0[gbase[p0] + lp0] = i;
    rowlist1[gbase[32 + p1] + lp1] = i;
}

// ---------------------------------------------------------------------------
// Transpose kernel: Bt[p][k][r] = B[p][r][k], At[p][r][o] = A[p][o][r].
// ---------------------------------------------------------------------------
__global__ __launch_bounds__(256) void transpose_kernel(
    const float* __restrict__ A, const float* __restrict__ B,
    float* __restrict__ At, float* __restrict__ Bt)
{
    __shared__ float T[16 * 68];
    __shared__ float U[64 * 20];
    const int tid = threadIdx.x;
    const int p = blockIdx.x;
    const float4* B4 = (const float4*)(B + (size_t)p * RNK * KDIM);
    const float4* A4 = (const float4*)(A + (size_t)p * OUTD * RNK);
    float4* Bt4 = (float4*)(Bt + (size_t)p * KDIM * RNK);
    float4* At4 = (float4*)(At + (size_t)p * RNK * OUTD);

    for (int c = 0; c < 16; ++c) {
        {
            int r = tid >> 4, kk = tid & 15;
            float4 v = B4[r * 256 + c * 16 + kk];
            *(float4*)&T[r * 68 + kk * 4] = v;
        }
        {
            int o = tid >> 2, rq = tid & 3;
            float4 v = A4[(c * 64 + o) * 4 + rq];
            *(float4*)&U[o * 20 + rq * 4] = v;
        }
        __syncthreads();
        {
            int k = tid >> 2, rq = tid & 3;
            float4 g = make_float4(T[(rq * 4 + 0) * 68 + k], T[(rq * 4 + 1) * 68 + k],
                                   T[(rq * 4 + 2) * 68 + k], T[(rq * 4 + 3) * 68 + k]);
            Bt4[(c * 64 + k) * 4 + rq] = g;
        }
        {
            int r = tid >> 4, ow = tid & 15;
            float4 g = make_float4(U[(ow * 4 + 0) * 20 + r], U[(ow * 4 + 1) * 20 + r],
                                   U[(ow * 4 + 2) * 20 + r], U[(ow * 4 + 3) * 20 + r]);
            At4[r * 256 + c * 16 + ow] = g;
        }
        __syncthreads();
    }
}

// ---------------------------------------------------------------------------
// Apply v6: CROWS=4, 2048 chunk-blocks per slot (8 blocks/CU -> 32 waves/CU).
//  h: thread (rw=tid>>6, kq=(tid>>2)&15, rq=tid&3): k = i*16+kq.
//     x: 64B/line broadcast. Bt: 1KB contiguous/instr (16B/lane). 4 indep
//     float4 accumulators, unroll 8.
//  reduce: wave 0, part[] padded on rw to avoid bank alias.
//  y: thread (rw, l=tid&63): At/bias/out 1KB contiguous per instr.
// ---------------------------------------------------------------------------
__global__ __launch_bounds__(256, 8) void apply6_kernel(
    const float* __restrict__ x, const float* __restrict__ At,
    const float* __restrict__ Bt, const float* __restrict__ bias,
    const float4* __restrict__ route, const int* __restrict__ rowlist,
    const int2* __restrict__ segs, float* __restrict__ out, int slot)
{
    __shared__ float part[CROWS][17][20];   // [rw][kq(16)+pad][rank(16)+pad]
    __shared__ float hs[CROWS][16];
    __shared__ int rows[CROWS];
    __shared__ float wrow[CROWS];

    const int tid = threadIdx.x;
    const int p = blockIdx.y;
    const int2 seg = segs[slot * 32 + p];
    const float4* Btp = (const float4*)(Bt + (size_t)p * KDIM * RNK);
    const float4* Atp = (const float4*)(At + (size_t)p * RNK * OUTD);
    const float4* bp  = (const float4*)(bias + (size_t)p * OUTD);

    for (int c = blockIdx.x; ; c += 64) {
        const int base = seg.x + c * CROWS;
        if (base >= seg.y) break;
        const int m = min(CROWS, seg.y - base);

        if (tid < CROWS) {
            int rr = rowlist[base + min(tid, m - 1)];
            rows[tid] = rr;
            float4 rt = route[rr];
            wrow[tid] = slot ? rt.w : rt.z;
        }
        __syncthreads();

        // ---- h phase ----
        {
            const int rw = tid >> 6, kq = (tid >> 2) & 15, rq = tid & 3;
            const float* xr = x + (size_t)rows[rw] * KDIM;
            float4 acc = {0.f, 0.f, 0.f, 0.f};
            #pragma unroll 8
            for (int i = 0; i < 64; ++i) {
                const int k = i * 16 + kq;
                float xv = xr[k];
                float4 b = Btp[k * 4 + rq];
                acc.x = fmaf(xv, b.x, acc.x);
                acc.y = fmaf(xv, b.y, acc.y);
                acc.z = fmaf(xv, b.z, acc.z);
                acc.w = fmaf(xv, b.w, acc.w);
            }
            *(float4*)(&part[rw][kq][rq * 4]) = acc;
        }
        __syncthreads();

        // ---- reduce over kq (wave 0) ----
        if (tid < 64) {
            const int rw = tid >> 4, r = tid & 15;
            float s = 0.f;
            #pragma unroll
            for (int kq = 0; kq < 16; ++kq) s += part[rw][kq][r];
            hs[rw][r] = s;
        }
        __syncthreads();

        // ---- y phase ----
        {
            const int rw = tid >> 6, l = tid & 63;
            if (rw < m) {
                float h[16];
                #pragma unroll
                for (int r = 0; r < 16; ++r) h[r] = hs[rw][r];
                const float wgt = wrow[rw];
                float* orow = out + (size_t)rows[rw] * OUTD;
                float4 a0 = bp[0 * 64 + l];
                float4 a1 = bp[1 * 64 + l];
                float4 a2 = bp[2 * 64 + l];
                float4 a3 = bp[3 * 64 + l];
                #pragma unroll 4
                for (int r = 0; r < 16; ++r) {
                    float4 q0 = Atp[r * 256 + 0 * 64 + l];
                    float4 q1 = Atp[r * 256 + 1 * 64 + l];
                    float4 q2 = Atp[r * 256 + 2 * 64 + l];
                    float4 q3 = Atp[r * 256 + 3 * 64 + l];
                    float hr = h[r];
                    a0.x = fmaf(hr, q0.x, a0.x); a0.y = fmaf(hr, q0.y, a0.y);
                    a0.z = fmaf(hr, q0.z, a0.z); a0.w = fmaf(hr, q0.w, a0.w);
                    a1.x = fmaf(hr, q1.x, a1.x); a1.y = fmaf(hr, q1.y, a1.y);
                    a1.z = fmaf(hr, q1.z, a1.z); a1.w = fmaf(hr, q1.w, a1.w);
                    a2.x = fmaf(hr, q2.x, a2.x); a2.y = fmaf(hr, q2.y, a2.y);
                    a2.z = fmaf(hr, q2.z, a2.z); a2.w = fmaf(hr, q2.w, a2.w);
                    a3.x = fmaf(hr, q3.x, a3.x); a3.y = fmaf(hr, q3.y, a3.y);
                    a3.z = fmaf(hr, q3.z, a3.z); a3.w = fmaf(hr, q3.w, a3.w);
                }
                #pragma unroll
                for (int j = 0; j < 4; ++j) {
                    float4 v = (j == 0) ? a0 : (j == 1) ? a1 : (j == 2) ? a2 : a3;
                    v.x *= wgt; v.y *= wgt; v.z *= wgt; v.w *= wgt;
                    float4* dst = (float4*)(orow + (j * 64 + l) * 4);
                    if (slot) {
                        float4 old = *dst;
                        v.x += old.x; v.y += old.y; v.z += old.z; v.w += old.w;
                    }
                    *dst = v;
                }
            }
        }
        __syncthreads();
    }
}

extern "C" void kernel_launch(void* const* d_in, const int* in_sizes, int n_in,
                              void* d_out, int out_size, void* d_ws, size_t ws_size,
                              hipStream_t stream) {
    const float* x     = (const float*)d_in[0];
    const float* proto = (const float*)d_in[1];
    const float* B     = (const float*)d_in[2];
    const float* A     = (const float*)d_in[3];
    const float* bias  = (const float*)d_in[4];
    const float* temp  = (const float*)d_in[5];
    float* out = (float*)d_out;

    char* wsb = (char*)d_ws;
    float4* route = (float4*)wsb;                      // 128 KB
    int* rowlist0 = (int*)(wsb + 131072);              // 32 KB
    int* rowlist1 = rowlist0 + ROWS_TOTAL;             // 32 KB
    int* counts   = rowlist1 + ROWS_TOTAL;             // 256 B
    int2* segs    = (int2*)(counts + 64);              // 512 B
    float* Bt     = (float*)(wsb + 262144);            // 2 MB
    float* At     = (float*)(wsb + 262144 + 2097152);  // 2 MB

    hipMemsetAsync(counts, 0, 64 * sizeof(int), stream);
    transpose_kernel<<<NPROTO, 256, 0, stream>>>(A, B, At, Bt);
    route_kernel<<<ROWS_TOTAL / 16, 256, 0, stream>>>(x, proto, temp, route, counts);
    scan_kernel<<<1, 64, 0, stream>>>(counts, segs);
    scatter_kernel<<<ROWS_TOTAL / 256, 256, 0, stream>>>(route, counts, rowlist0, rowlist1);
    dim3 agrid(64, NPROTO);
    apply6_kernel<<<agrid, 256, 0, stream>>>(x, At, Bt, bias, route, rowlist0, segs, out, 0);
    apply6_kernel<<<agrid, 256, 0, stream>>>(x, At, Bt, bias, route, rowlist1, segs, out, 1);
}

// Round 13
// 208.984 us; speedup vs baseline: 3.0746x; 1.2211x over previous
//
#include <hip/hip_runtime.h>
#include <math.h>

#define ROWS_TOTAL 8192
#define KDIM 1024
#define NPROTO 32
#define RNK 16
#define OUTD 1024
#define TIE_EPS 1.30e-4

// ---------------------------------------------------------------------------
// Kernel 1: routing (numerics identical to the PASSING round-7 kernel).
// ---------------------------------------------------------------------------
__global__ __launch_bounds__(256) void route_kernel(
    const float* __restrict__ x, const float* __restrict__ proto,
    const float* __restrict__ temp, float4* __restrict__ route,
    int* __restrict__ counts)
{
    __shared__ float Xs[16][68];
    __shared__ float Ps[64][33];
    __shared__ double x2s[16];
    __shared__ double p2s[32];
    __shared__ int lcnt[64];

    const int tid = threadIdx.x;
    const int rowbase = blockIdx.x * 16;
    const int frow = tid >> 4;
    const int fq   = tid & 15;
    const int c    = tid & 31;
    const int rg   = tid >> 5;

    if (tid < 64) lcnt[tid] = 0;

    double xsq = 0.0, p2a = 0.0, p2b = 0.0;
    double acc0 = 0.0, acc1 = 0.0;

    for (int kc = 0; kc < KDIM; kc += 64) {
        float4 xv = *(const float4*)(x + (rowbase + frow) * KDIM + kc + 4 * fq);
        xsq = fma((double)xv.x, (double)xv.x, xsq);
        xsq = fma((double)xv.y, (double)xv.y, xsq);
        xsq = fma((double)xv.z, (double)xv.z, xsq);
        xsq = fma((double)xv.w, (double)xv.w, xsq);
        *(float4*)(&Xs[frow][4 * fq]) = xv;
        float4 pa = *(const float4*)(proto + frow * KDIM + kc + 4 * fq);
        float4 pb = *(const float4*)(proto + (frow + 16) * KDIM + kc + 4 * fq);
        p2a = fma((double)pa.x, (double)pa.x, p2a);
        p2a = fma((double)pa.y, (double)pa.y, p2a);
        p2a = fma((double)pa.z, (double)pa.z, p2a);
        p2a = fma((double)pa.w, (double)pa.w, p2a);
        p2b = fma((double)pb.x, (double)pb.x, p2b);
        p2b = fma((double)pb.y, (double)pb.y, p2b);
        p2b = fma((double)pb.z, (double)pb.z, p2b);
        p2b = fma((double)pb.w, (double)pb.w, p2b);
        Ps[4 * fq + 0][frow] = pa.x;
        Ps[4 * fq + 1][frow] = pa.y;
        Ps[4 * fq + 2][frow] = pa.z;
        Ps[4 * fq + 3][frow] = pa.w;
        Ps[4 * fq + 0][frow + 16] = pb.x;
        Ps[4 * fq + 1][frow + 16] = pb.y;
        Ps[4 * fq + 2][frow + 16] = pb.z;
        Ps[4 * fq + 3][frow + 16] = pb.w;
        __syncthreads();
        #pragma unroll
        for (int k = 0; k < 64; k += 4) {
            float4 xa = *(const float4*)(&Xs[2 * rg][k]);
            float4 xb = *(const float4*)(&Xs[2 * rg + 1][k]);
            double q0 = (double)Ps[k][c],     q1 = (double)Ps[k + 1][c];
            double q2 = (double)Ps[k + 2][c], q3 = (double)Ps[k + 3][c];
            acc0 = fma((double)xa.x, q0, acc0);
            acc0 = fma((double)xa.y, q1, acc0);
            acc0 = fma((double)xa.z, q2, acc0);
            acc0 = fma((double)xa.w, q3, acc0);
            acc1 = fma((double)xb.x, q0, acc1);
            acc1 = fma((double)xb.y, q1, acc1);
            acc1 = fma((double)xb.z, q2, acc1);
            acc1 = fma((double)xb.w, q3, acc1);
        }
        __syncthreads();
    }

    #pragma unroll
    for (int m = 1; m < 16; m <<= 1) {
        xsq += __shfl_xor(xsq, m);
        p2a += __shfl_xor(p2a, m);
        p2b += __shfl_xor(p2b, m);
    }
    if (fq == 0) { x2s[frow] = xsq; p2s[frow] = p2a; p2s[frow + 16] = p2b; }
    __syncthreads();

    const double tmp = (double)fmaxf(fabsf(temp[0]), 0.1f);
    const double myp2 = p2s[c];

    #pragma unroll
    for (int which = 0; which < 2; ++which) {
        double key = myp2 - 2.0 * (which ? acc1 : acc0);
        double k1 = key, k2 = 1.0e300, k3 = 1.1e300;
        int    i1 = c,   i2 = 64,      i3 = 65;
        #pragma unroll
        for (int m = 1; m < 32; m <<= 1) {
            double b1 = __shfl_xor(k1, m), b2 = __shfl_xor(k2, m), b3 = __shfl_xor(k3, m);
            int    j1 = __shfl_xor(i1, m), j2 = __shfl_xor(i2, m), j3 = __shfl_xor(i3, m);
            bool c1 = k1 <= b1;
            double m1 = c1 ? k1 : b1, M1 = c1 ? b1 : k1;
            int   mi1 = c1 ? i1 : j1, Mi1 = c1 ? j1 : i1;
            bool c2 = k2 <= b2;
            double m2 = c2 ? k2 : b2;
            int   mi2 = c2 ? i2 : j2;
            bool c3 = k3 <= b3;
            double m3 = c3 ? k3 : b3;
            int   mi3 = c3 ? i3 : j3;
            bool c4 = M1 <= m2;
            double t2 = c4 ? M1 : m2,  T2 = c4 ? m2 : M1;
            int   ti2 = c4 ? Mi1 : mi2, Ti2 = c4 ? mi2 : Mi1;
            bool c5 = T2 <= m3;
            k1 = m1; i1 = mi1;
            k2 = t2; i2 = ti2;
            k3 = c5 ? T2 : m3; i3 = c5 ? Ti2 : mi3;
        }
        if (c == 0) {
            const int row = rowbase + 2 * rg + which;
            bool tie = (k3 - k2) < TIE_EPS;
            bool take3 = tie && (i3 < i2);
            double ksel = take3 ? k3 : k2;
            int    isel = take3 ? i3 : i2;
            double x2 = x2s[2 * rg + which];
            double d0 = sqrt(fmax(x2 + k1, 0.0));
            double d1 = sqrt(fmax(x2 + ksel, 0.0));
            float e  = expf((float)((d0 - d1) / tmp));
            float w0 = 1.f / (1.f + e);
            route[row] = make_float4(__int_as_float(i1), __int_as_float(isel),
                                     w0, e * w0);
            atomicAdd(&lcnt[i1], 1);
            atomicAdd(&lcnt[32 + isel], 1);
        }
    }
    __syncthreads();
    if (tid < 64) atomicAdd(&counts[tid], lcnt[tid]);
}

__global__ __launch_bounds__(64) void scan_kernel(int* __restrict__ counts)
{
    const int tid = threadIdx.x;
    int v = counts[tid];
    int sum = v;
    #pragma unroll
    for (int off = 1; off < 32; off <<= 1) {
        int u = __shfl_up(sum, off, 32);
        if ((tid & 31) >= off) sum += u;
    }
    counts[tid] = sum - v;
}

__global__ __launch_bounds__(256) void scatter_kernel(
    const float4* __restrict__ route, int* __restrict__ counts,
    int* __restrict__ rowlist0, int* __restrict__ rowlist1)
{
    __shared__ int lcnt[64];
    __shared__ int gbase[64];
    const int tid = threadIdx.x;
    const int i = blockIdx.x * 256 + tid;
    if (tid < 64) lcnt[tid] = 0;
    __syncthreads();
    float4 rt = route[i];
    int p0 = __float_as_int(rt.x);
    int p1 = __float_as_int(rt.y);
    int lp0 = atomicAdd(&lcnt[p0], 1);
    int lp1 = atomicAdd(&lcnt[32 + p1], 1);
    __syncthreads();
    if (tid < 64) gbase[tid] = atomicAdd(&counts[tid], lcnt[tid]);
    __syncthreads();
    rowlist0[gbase[p0] + lp0] = i;
    rowlist1[gbase[32 + p1] + lp1] = i;
}

// ---------------------------------------------------------------------------
// Transpose kernel: Bt[p][k][r] = B[p][r][k], At[p][r][o] = A[p][o][r].
// ---------------------------------------------------------------------------
__global__ __launch_bounds__(256) void transpose_kernel(
    const float* __restrict__ A, const float* __restrict__ B,
    float* __restrict__ At, float* __restrict__ Bt)
{
    __shared__ float T[16 * 68];
    __shared__ float U[64 * 20];
    const int tid = threadIdx.x;
    const int p = blockIdx.x;
    const float4* B4 = (const float4*)(B + (size_t)p * RNK * KDIM);
    const float4* A4 = (const float4*)(A + (size_t)p * OUTD * RNK);
    float4* Bt4 = (float4*)(Bt + (size_t)p * KDIM * RNK);
    float4* At4 = (float4*)(At + (size_t)p * RNK * OUTD);

    for (int c = 0; c < 16; ++c) {
        {
            int r = tid >> 4, kk = tid & 15;
            float4 v = B4[r * 256 + c * 16 + kk];
            *(float4*)&T[r * 68 + kk * 4] = v;
        }
        {
            int o = tid >> 2, rq = tid & 3;
            float4 v = A4[(c * 64 + o) * 4 + rq];
            *(float4*)&U[o * 20 + rq * 4] = v;
        }
        __syncthreads();
        {
            int k = tid >> 2, rq = tid & 3;
            float4 g = make_float4(T[(rq * 4 + 0) * 68 + k], T[(rq * 4 + 1) * 68 + k],
                                   T[(rq * 4 + 2) * 68 + k], T[(rq * 4 + 3) * 68 + k]);
            Bt4[(c * 64 + k) * 4 + rq] = g;
        }
        {
            int r = tid >> 4, ow = tid & 15;
            float4 g = make_float4(U[(ow * 4 + 0) * 20 + r], U[(ow * 4 + 1) * 20 + r],
                                   U[(ow * 4 + 2) * 20 + r], U[(ow * 4 + 3) * 20 + r]);
            At4[r * 256 + c * 16 + ow] = g;
        }
        __syncthreads();
    }
}

// ---------------------------------------------------------------------------
// Apply v7: 512 blocks/slot; each WAVE owns 4 consecutive sorted-list entries
// (one proto per quad except rare segment boundaries -> 4x-redundant
// fallback). Wave stages its 4 x-rows to private LDS (no barriers anywhere).
// h: one Bt float4 load feeds 4 rows (4x intensity); kq/rq lane mapping, xor
//    reduce + shfl broadcast h[16] x4 into regs.
// y: one At float4 load feeds 4 rows; At/bias/out 1KB-contiguous per instr.
// slot0 stores w*(y+b), slot1 accumulates (stream-ordered, race-free).
// ---------------------------------------------------------------------------
__global__ __launch_bounds__(256) void apply7_kernel(
    const float* __restrict__ x, const float* __restrict__ At,
    const float* __restrict__ Bt, const float* __restrict__ bias,
    const float4* __restrict__ route, const int* __restrict__ rowlist,
    float* __restrict__ out, int slot)
{
    __shared__ __align__(16) float Xs[16 * KDIM];   // 64 KB, per-wave quarters

    const int tid = threadIdx.x;
    const int w = tid >> 6, l = tid & 63;
    const int e0 = blockIdx.x * 16 + w * 4;

    int rws[4]; int ps[4]; float wts[4];
    #pragma unroll
    for (int j = 0; j < 4; ++j) {
        int rr = rowlist[e0 + j];
        rws[j] = rr;
        float4 rt = route[rr];
        ps[j] = __float_as_int(slot ? rt.y : rt.x);
        wts[j] = slot ? rt.w : rt.z;
    }
    const bool uni = (ps[0] == ps[1]) && (ps[1] == ps[2]) && (ps[2] == ps[3]);

    // stage this wave's 4 x rows into its LDS quarter (wave-local)
    float* Xw = &Xs[w * 4 * KDIM];
    #pragma unroll
    for (int j = 0; j < 4; ++j) {
        const float4* xr = (const float4*)(x + (size_t)rws[j] * KDIM);
        float4* dst = (float4*)(Xw + j * KDIM);
        #pragma unroll
        for (int q = 0; q < 4; ++q) dst[q * 64 + l] = xr[q * 64 + l];
    }

    const int kq = l >> 2, rq = l & 3;
    const int reps = uni ? 1 : 4;

    for (int rep = 0; rep < reps; ++rep) {
        const int p = uni ? ps[0] : ps[rep];
        const float* X0 = Xw + (uni ? 0 : rep) * KDIM;
        const float* X1 = Xw + (uni ? 1 : rep) * KDIM;
        const float* X2 = Xw + (uni ? 2 : rep) * KDIM;
        const float* X3 = Xw + (uni ? 3 : rep) * KDIM;
        const float4* Btp = (const float4*)(Bt + (size_t)p * KDIM * RNK);
        const float4* Atp = (const float4*)(At + (size_t)p * RNK * OUTD);
        const float4* bp  = (const float4*)(bias + (size_t)p * OUTD);

        // ---- h phase ----
        float4 a0 = {0,0,0,0}, a1 = {0,0,0,0}, a2 = {0,0,0,0}, a3 = {0,0,0,0};
        #pragma unroll 8
        for (int i = 0; i < 64; ++i) {
            const int k = i * 16 + kq;
            float4 bv = Btp[k * 4 + rq];
            float xv0 = X0[k], xv1 = X1[k], xv2 = X2[k], xv3 = X3[k];
            a0.x = fmaf(xv0, bv.x, a0.x); a0.y = fmaf(xv0, bv.y, a0.y);
            a0.z = fmaf(xv0, bv.z, a0.z); a0.w = fmaf(xv0, bv.w, a0.w);
            a1.x = fmaf(xv1, bv.x, a1.x); a1.y = fmaf(xv1, bv.y, a1.y);
            a1.z = fmaf(xv1, bv.z, a1.z); a1.w = fmaf(xv1, bv.w, a1.w);
            a2.x = fmaf(xv2, bv.x, a2.x); a2.y = fmaf(xv2, bv.y, a2.y);
            a2.z = fmaf(xv2, bv.z, a2.z); a2.w = fmaf(xv2, bv.w, a2.w);
            a3.x = fmaf(xv3, bv.x, a3.x); a3.y = fmaf(xv3, bv.y, a3.y);
            a3.z = fmaf(xv3, bv.z, a3.z); a3.w = fmaf(xv3, bv.w, a3.w);
        }
        // reduce over kq (lane bits 2..5)
        #pragma unroll
        for (int m = 4; m < 64; m <<= 1) {
            a0.x += __shfl_xor(a0.x, m); a0.y += __shfl_xor(a0.y, m);
            a0.z += __shfl_xor(a0.z, m); a0.w += __shfl_xor(a0.w, m);
            a1.x += __shfl_xor(a1.x, m); a1.y += __shfl_xor(a1.y, m);
            a1.z += __shfl_xor(a1.z, m); a1.w += __shfl_xor(a1.w, m);
            a2.x += __shfl_xor(a2.x, m); a2.y += __shfl_xor(a2.y, m);
            a2.z += __shfl_xor(a2.z, m); a2.w += __shfl_xor(a2.w, m);
            a3.x += __shfl_xor(a3.x, m); a3.y += __shfl_xor(a3.y, m);
            a3.z += __shfl_xor(a3.z, m); a3.w += __shfl_xor(a3.w, m);
        }
        // lane (kq,rq) now holds h_j[rq*4+c]; broadcast all 16 per row
        float h0[16], h1[16], h2[16], h3[16];
        #pragma unroll
        for (int r = 0; r < 16; ++r) {
            const int src = r >> 2;   // lane with rq == r>>2 (lanes 0..3)
            const int cc = r & 3;
            float v0 = (cc == 0) ? a0.x : (cc == 1) ? a0.y : (cc == 2) ? a0.z : a0.w;
            float v1 = (cc == 0) ? a1.x : (cc == 1) ? a1.y : (cc == 2) ? a1.z : a1.w;
            float v2 = (cc == 0) ? a2.x : (cc == 1) ? a2.y : (cc == 2) ? a2.z : a2.w;
            float v3 = (cc == 0) ? a3.x : (cc == 1) ? a3.y : (cc == 2) ? a3.z : a3.w;
            h0[r] = __shfl(v0, src);
            h1[r] = __shfl(v1, src);
            h2[r] = __shfl(v2, src);
            h3[r] = __shfl(v3, src);
        }

        // ---- y phase ----
        const float wg0 = uni ? wts[0] : wts[rep];
        const float wg1 = wts[1], wg2 = wts[2], wg3 = wts[3];
        float* o0 = out + (size_t)(uni ? rws[0] : rws[rep]) * OUTD;
        float* o1 = out + (size_t)rws[1] * OUTD;
        float* o2 = out + (size_t)rws[2] * OUTD;
        float* o3 = out + (size_t)rws[3] * OUTD;

        #pragma unroll
        for (int jj = 0; jj < 4; ++jj) {
            const int f4 = jj * 64 + l;
            float4 bb = bp[f4];
            float4 c0 = bb, c1 = bb, c2 = bb, c3 = bb;
            #pragma unroll
            for (int r = 0; r < 16; ++r) {
                float4 a = Atp[r * 256 + f4];
                c0.x = fmaf(h0[r], a.x, c0.x); c0.y = fmaf(h0[r], a.y, c0.y);
                c0.z = fmaf(h0[r], a.z, c0.z); c0.w = fmaf(h0[r], a.w, c0.w);
                c1.x = fmaf(h1[r], a.x, c1.x); c1.y = fmaf(h1[r], a.y, c1.y);
                c1.z = fmaf(h1[r], a.z, c1.z); c1.w = fmaf(h1[r], a.w, c1.w);
                c2.x = fmaf(h2[r], a.x, c2.x); c2.y = fmaf(h2[r], a.y, c2.y);
                c2.z = fmaf(h2[r], a.z, c2.z); c2.w = fmaf(h2[r], a.w, c2.w);
                c3.x = fmaf(h3[r], a.x, c3.x); c3.y = fmaf(h3[r], a.y, c3.y);
                c3.z = fmaf(h3[r], a.z, c3.z); c3.w = fmaf(h3[r], a.w, c3.w);
            }
            float4 v0 = make_float4(wg0 * c0.x, wg0 * c0.y, wg0 * c0.z, wg0 * c0.w);
            float4* d0 = (float4*)(o0 + f4 * 4);
            if (slot) { float4 od = *d0; v0.x += od.x; v0.y += od.y; v0.z += od.z; v0.w += od.w; }
            *d0 = v0;
            if (uni) {
                float4 v1 = make_float4(wg1 * c1.x, wg1 * c1.y, wg1 * c1.z, wg1 * c1.w);
                float4 v2 = make_float4(wg2 * c2.x, wg2 * c2.y, wg2 * c2.z, wg2 * c2.w);
                float4 v3 = make_float4(wg3 * c3.x, wg3 * c3.y, wg3 * c3.z, wg3 * c3.w);
                float4* d1 = (float4*)(o1 + f4 * 4);
                float4* d2 = (float4*)(o2 + f4 * 4);
                float4* d3 = (float4*)(o3 + f4 * 4);
                if (slot) {
                    float4 q1 = *d1, q2 = *d2, q3 = *d3;
                    v1.x += q1.x; v1.y += q1.y; v1.z += q1.z; v1.w += q1.w;
                    v2.x += q2.x; v2.y += q2.y; v2.z += q2.z; v2.w += q2.w;
                    v3.x += q3.x; v3.y += q3.y; v3.z += q3.z; v3.w += q3.w;
                }
                *d1 = v1; *d2 = v2; *d3 = v3;
            }
        }
    }
}

extern "C" void kernel_launch(void* const* d_in, const int* in_sizes, int n_in,
                              void* d_out, int out_size, void* d_ws, size_t ws_size,
                              hipStream_t stream) {
    const float* x     = (const float*)d_in[0];
    const float* proto = (const float*)d_in[1];
    const float* B     = (const float*)d_in[2];
    const float* A     = (const float*)d_in[3];
    const float* bias  = (const float*)d_in[4];
    const float* temp  = (const float*)d_in[5];
    float* out = (float*)d_out;

    char* wsb = (char*)d_ws;
    float4* route = (float4*)wsb;                      // 128 KB
    int* rowlist0 = (int*)(wsb + 131072);              // 32 KB
    int* rowlist1 = rowlist0 + ROWS_TOTAL;             // 32 KB
    int* counts   = rowlist1 + ROWS_TOTAL;             // 256 B
    float* Bt     = (float*)(wsb + 262144);            // 2 MB
    float* At     = (float*)(wsb + 262144 + 2097152);  // 2 MB

    hipMemsetAsync(counts, 0, 64 * sizeof(int), stream);
    transpose_kernel<<<NPROTO, 256, 0, stream>>>(A, B, At, Bt);
    route_kernel<<<ROWS_TOTAL / 16, 256, 0, stream>>>(x, proto, temp, route, counts);
    scan_kernel<<<1, 64, 0, stream>>>(counts);
    scatter_kernel<<<ROWS_TOTAL / 256, 256, 0, stream>>>(route, counts, rowlist0, rowlist1);
    apply7_kernel<<<ROWS_TOTAL / 16, 256, 0, stream>>>(x, At, Bt, bias, route, rowlist0, out, 0);
    apply7_kernel<<<ROWS_TOTAL / 16, 256, 0, stream>>>(x, At, Bt, bias, route, rowlist1, out, 1);
}